// Round 11
// baseline (447.200 us; speedup 1.0000x reference)
//
#include <hip/hip_runtime.h>
#include <math.h>

#define N_NODES 100000
#define IN_DIM  128
#define HIDDEN  64
#define N_EDGES 1600000

// ---------------------------------------------------------------------------
// Workspace layout (4-byte units) — R8 path A layout (verified):
//   [0,       100000)   weights  (float)   per-node gate
//   [100000,  200000)   counts   (int)     per-node in-degree
//   [200000,  300000)   cursor   (int)     UNUSED (rank trick)
//   [300000,  300016)   counter  (int)     global bump allocator
//   [300016,  400016)   base     (int)     per-node segment base in bucket
//   [400016, 2000016)   bucket   (int)     edge source (col) grouped by row
//   [2000016,8400016)   x_bf16   (ushort)  RNE bf16 mirror of x
// Scratch: rank[e] (1.6M ints) lives in the OUT buffer, dead until gather
// rewrites every row of it.
//
// R9 LESSON (mega_kernel, 197 us): fusing the scattered bucket store as a
// DEPENDENT op after the atomic doubled the binning time (110 -> 200) at
// <12% HBM / <11% VALU -> the binning phase is LATENCY x CONCURRENCY bound,
// not atomic-throughput bound. Padded-bucket fusion reverted; instead R10
// batches 4 INDEPENDENT chains per thread (hist x4, fill x4).
// ---------------------------------------------------------------------------
#define WS_WEIGHTS 0
#define WS_COUNTS  100000
#define WS_CURSOR  200000
#define WS_COUNTER 300000
#define WS_BASE    300016
#define WS_BUCKET  400016
#define WS_XBF16   2000016
#define WS_TOTAL   2000016                      // path B requirement
#define WS_TOTAL2  (WS_XBF16 + 6400000)         // path A: 33.6 MB

#define NB_GATE  ((N_NODES + 63) / 64)          // 1563
#define NB_HIST  ((N_EDGES + 255) / 256)        // 6250 (1 edge/thread, path B)
#define NB_HIST4 ((N_EDGES / 4 + 255) / 256)    // 1563 (4 edges/thread)
#define NB_CONV  ((N_NODES * IN_DIM / 8 + 255) / 256)  // 6250 (exact)

__global__ __launch_bounds__(256) void zero_f4_kernel(float4* __restrict__ p, int n4)
{
    const int i = blockIdx.x * 256 + threadIdx.x;
    if (i < n4) p[i] = make_float4(0.f, 0.f, 0.f, 0.f);
}

__device__ __forceinline__ unsigned int bf16_rne(float f)
{
    const unsigned int u = __float_as_uint(f);
    return (u + 0x7FFFu + ((u >> 16) & 1u)) >> 16;
}

// ---------------------------------------------------------------------------
// Gate body (v6, verified): 4 threads per node, 64 nodes per block;
// wave-uniform W_sim addresses; 4-wave LDS reduction.
// ---------------------------------------------------------------------------
__device__ __forceinline__ void gate_body(
    int gblock,
    const float* __restrict__ x, const float* __restrict__ W_sim,
    const float* __restrict__ b_sim, const float* __restrict__ w_vec,
    const float* __restrict__ b_vec, float* __restrict__ weights)
{
    __shared__ float part[4][64];
    const int lane  = threadIdx.x & 63;
    const int w     = __builtin_amdgcn_readfirstlane(threadIdx.x >> 6);
    const int jb    = 16 * w;
    const int node  = gblock * 64 + lane;
    const bool valid = node < N_NODES;
    const float4* xr = (const float4*)(x + (size_t)(valid ? node : 0) * IN_DIM);

    float acc[16];
#pragma unroll
    for (int j = 0; j < 16; ++j) acc[j] = b_sim[jb + j];

    for (int k4 = 0; k4 < IN_DIM / 4; ++k4) {
        const float4 a = xr[k4];
#pragma unroll
        for (int j = 0; j < 16; ++j) {
            acc[j] += a.x * W_sim[(4 * k4 + 0) * HIDDEN + jb + j];
            acc[j] += a.y * W_sim[(4 * k4 + 1) * HIDDEN + jb + j];
            acc[j] += a.z * W_sim[(4 * k4 + 2) * HIDDEN + jb + j];
            acc[j] += a.w * W_sim[(4 * k4 + 3) * HIDDEN + jb + j];
        }
    }

    float p = 0.f;
#pragma unroll
    for (int j = 0; j < 16; ++j)
        p += tanhf(acc[j]) * w_vec[jb + j];

    part[w][lane] = p;
    __syncthreads();

    if (threadIdx.x < 64) {
        const float g = part[0][lane] + part[1][lane] + part[2][lane] + part[3][lane];
        if (valid)
            weights[node] = 1.f / (1.f + expf(-(g + b_vec[0])));
    }
}

// Standalone gate (fallback path C only).
__global__ __launch_bounds__(256) void gate_kernel(
    const float* __restrict__ x, const float* __restrict__ W_sim,
    const float* __restrict__ b_sim, const float* __restrict__ w_vec,
    const float* __restrict__ b_vec, float* __restrict__ weights)
{
    gate_body(blockIdx.x, x, W_sim, b_sim, w_vec, b_vec, weights);
}

// ---------------------------------------------------------------------------
// R10 fused gate + hist(x4) + conv.
// hist x4: each thread owns 4 edges — int4-coalesced row load, 4 INDEPENDENT
// atomicAdds in flight (R9 evidence: binning is latency-bound, chain length
// per thread is what matters), int4-coalesced rank store.
// Hist blocks FIRST so the atomic pacer starts at t=0; conv+gate backfill.
// ---------------------------------------------------------------------------
__global__ __launch_bounds__(256) void gate_hist_conv_kernel(
    const float* __restrict__ x, const float* __restrict__ W_sim,
    const float* __restrict__ b_sim, const float* __restrict__ w_vec,
    const float* __restrict__ b_vec, float* __restrict__ weights,
    const int* __restrict__ edge_index, int* __restrict__ counts,
    int* __restrict__ rank /* = out buffer scratch */,
    unsigned int* __restrict__ xb16)
{
    if (blockIdx.x < NB_HIST4) {
        const int t4 = blockIdx.x * 256 + threadIdx.x;
        if (t4 * 4 < N_EDGES) {                      // N_EDGES % 4 == 0
            const int4 rows = ((const int4*)edge_index)[t4];
            int4 rk;
            rk.x = atomicAdd(&counts[rows.x], 1);
            rk.y = atomicAdd(&counts[rows.y], 1);
            rk.z = atomicAdd(&counts[rows.z], 1);
            rk.w = atomicAdd(&counts[rows.w], 1);
            ((int4*)rank)[t4] = rk;
        }
        return;
    }
    if (blockIdx.x < NB_HIST4 + NB_CONV) {
        const int t = (blockIdx.x - NB_HIST4) * 256 + threadIdx.x; // [0,1.6M)
        const float4* src = (const float4*)x;
        const float4 a = src[2 * t + 0];
        const float4 b = src[2 * t + 1];
        uint4 o;
        o.x = bf16_rne(a.x) | (bf16_rne(a.y) << 16);
        o.y = bf16_rne(a.z) | (bf16_rne(a.w) << 16);
        o.z = bf16_rne(b.x) | (bf16_rne(b.y) << 16);
        o.w = bf16_rne(b.z) | (bf16_rne(b.w) << 16);
        ((uint4*)xb16)[t] = o;
        return;
    }
    gate_body(blockIdx.x - NB_HIST4 - NB_CONV, x, W_sim, b_sim, w_vec, b_vec, weights);
}

// Path B variant (no conv), 1 edge/thread — kept verified-as-is.
__global__ __launch_bounds__(256) void gate_hist_kernel(
    const float* __restrict__ x, const float* __restrict__ W_sim,
    const float* __restrict__ b_sim, const float* __restrict__ w_vec,
    const float* __restrict__ b_vec, float* __restrict__ weights,
    const int* __restrict__ edge_index, int* __restrict__ counts,
    int* __restrict__ rank)
{
    if (blockIdx.x < NB_HIST) {
        const int e = blockIdx.x * 256 + threadIdx.x;
        if (e < N_EDGES) {
            const int row = edge_index[e];
            rank[e] = atomicAdd(&counts[row], 1);
        }
        return;
    }
    gate_body(blockIdx.x - NB_HIST, x, W_sim, b_sim, w_vec, b_vec, weights);
}

__global__ __launch_bounds__(256) void alloc_kernel(
    const int* __restrict__ counts, int* __restrict__ base, int* __restrict__ counter)
{
    const int node = blockIdx.x * 256 + threadIdx.x;
    const int lane = threadIdx.x & 63;
    const int c = (node < N_NODES) ? counts[node] : 0;

    int incl = c;
#pragma unroll
    for (int off = 1; off < 64; off <<= 1) {
        int v = __shfl_up(incl, off, 64);
        if (lane >= off) incl += v;
    }
    const int excl = incl - c;
    int wbase = 0;
    if (lane == 63) wbase = atomicAdd(counter, incl);
    wbase = __shfl(wbase, 63, 64);

    if (node < N_NODES) base[node] = wbase + excl;
}

// ---------------------------------------------------------------------------
// Fill v3 (R10): atomic-free AND x4-batched — 4 independent
// load(base)+store(bucket) chains per thread; edge/rank IO int4-coalesced.
// ---------------------------------------------------------------------------
__global__ __launch_bounds__(256) void fill_kernel(
    const int* __restrict__ edge_index, const int* __restrict__ base,
    const int* __restrict__ rank, int* __restrict__ bucket)
{
    const int t4 = blockIdx.x * 256 + threadIdx.x;
    if (t4 * 4 >= N_EDGES) return;
    const int4 rows = ((const int4*)edge_index)[t4];
    const int4 cols = ((const int4*)(edge_index + N_EDGES))[t4];
    const int4 rk   = ((const int4*)rank)[t4];
    const int b0 = base[rows.x];
    const int b1 = base[rows.y];
    const int b2 = base[rows.z];
    const int b3 = base[rows.w];
    bucket[b0 + rk.x] = cols.x;
    bucket[b1 + rk.y] = cols.y;
    bucket[b2 + rk.z] = cols.z;
    bucket[b3 + rk.w] = cols.w;
}

// ---------------------------------------------------------------------------
// Gather v4 (R8, verified): bf16 mirror, bytes-bound (~halved row traffic).
// ---------------------------------------------------------------------------
__global__ __launch_bounds__(256) void gather_bf16_kernel(
    const unsigned short* __restrict__ xb, const float* __restrict__ weights,
    const int* __restrict__ counts, const int* __restrict__ base,
    const int* __restrict__ bucket, float* __restrict__ readout)
{
    const int wave = threadIdx.x >> 6;
    const int lane = threadIdx.x & 63;
    const int half = lane >> 5;
    const int l32  = lane & 31;
    const int node = blockIdx.x * 4 + wave;
    if (node >= N_NODES) return;

    const int m = counts[node];
    const int b = base[node];
    const int m0  = (m + 1) >> 1;
    const int beg = half ? m0 : 0;
    const int end = half ? m  : m0;

    float4 acc0 = make_float4(0.f, 0.f, 0.f, 0.f);
    float4 acc1 = make_float4(0.f, 0.f, 0.f, 0.f);

#define BF2F(us) __uint_as_float(((unsigned int)(us)) << 16)
    int i = beg;
    for (; i + 2 <= end; i += 2) {
        const int c0 = bucket[b + i + 0];
        const int c1 = bucket[b + i + 1];
        const float w0 = weights[c0];
        const float w1 = weights[c1];
        const ushort4 v0 = ((const ushort4*)(xb + (size_t)c0 * IN_DIM))[l32];
        const ushort4 v1 = ((const ushort4*)(xb + (size_t)c1 * IN_DIM))[l32];
        acc0.x += BF2F(v0.x) * w0; acc0.y += BF2F(v0.y) * w0;
        acc0.z += BF2F(v0.z) * w0; acc0.w += BF2F(v0.w) * w0;
        acc1.x += BF2F(v1.x) * w1; acc1.y += BF2F(v1.y) * w1;
        acc1.z += BF2F(v1.z) * w1; acc1.w += BF2F(v1.w) * w1;
    }
    if (i < end) {
        const int c = bucket[b + i];
        const float wv = weights[c];
        const ushort4 v = ((const ushort4*)(xb + (size_t)c * IN_DIM))[l32];
        acc0.x += BF2F(v.x) * wv; acc0.y += BF2F(v.y) * wv;
        acc0.z += BF2F(v.z) * wv; acc0.w += BF2F(v.w) * wv;
    }
#undef BF2F
    acc0.x += acc1.x; acc0.y += acc1.y; acc0.z += acc1.z; acc0.w += acc1.w;

    acc0.x += __shfl(acc0.x, lane ^ 32, 64);
    acc0.y += __shfl(acc0.y, lane ^ 32, 64);
    acc0.z += __shfl(acc0.z, lane ^ 32, 64);
    acc0.w += __shfl(acc0.w, lane ^ 32, 64);

    if (half == 0)
        ((float4*)(readout + (size_t)node * IN_DIM))[l32] = acc0;
}

// Path B f32 gather (R7 verified).
__global__ __launch_bounds__(256) void gather_kernel(
    const float* __restrict__ x, const float* __restrict__ weights,
    const int* __restrict__ counts, const int* __restrict__ base,
    const int* __restrict__ bucket, float* __restrict__ readout)
{
    const int wave = threadIdx.x >> 6;
    const int lane = threadIdx.x & 63;
    const int half = lane >> 5;
    const int l32  = lane & 31;
    const int node = blockIdx.x * 4 + wave;
    if (node >= N_NODES) return;

    const int m = counts[node];
    const int b = base[node];
    const int m0  = (m + 1) >> 1;
    const int beg = half ? m0 : 0;
    const int end = half ? m  : m0;

    float4 acc0 = make_float4(0.f, 0.f, 0.f, 0.f);
    float4 acc1 = make_float4(0.f, 0.f, 0.f, 0.f);

    int i = beg;
    for (; i + 2 <= end; i += 2) {
        const int c0 = bucket[b + i + 0];
        const int c1 = bucket[b + i + 1];
        const float w0 = weights[c0];
        const float w1 = weights[c1];
        const float4 r0 = ((const float4*)(x + (size_t)c0 * IN_DIM))[l32];
        const float4 r1 = ((const float4*)(x + (size_t)c1 * IN_DIM))[l32];
        acc0.x += r0.x * w0; acc0.y += r0.y * w0; acc0.z += r0.z * w0; acc0.w += r0.w * w0;
        acc1.x += r1.x * w1; acc1.y += r1.y * w1; acc1.z += r1.z * w1; acc1.w += r1.w * w1;
    }
    if (i < end) {
        const int c = bucket[b + i];
        const float wv = weights[c];
        const float4 r = ((const float4*)(x + (size_t)c * IN_DIM))[l32];
        acc0.x += r.x * wv; acc0.y += r.y * wv; acc0.z += r.z * wv; acc0.w += r.w * wv;
    }
    acc0.x += acc1.x; acc0.y += acc1.y; acc0.z += acc1.z; acc0.w += acc1.w;

    acc0.x += __shfl(acc0.x, lane ^ 32, 64);
    acc0.y += __shfl(acc0.y, lane ^ 32, 64);
    acc0.z += __shfl(acc0.z, lane ^ 32, 64);
    acc0.w += __shfl(acc0.w, lane ^ 32, 64);

    if (half == 0)
        ((float4*)(readout + (size_t)node * IN_DIM))[l32] = acc0;
}

__global__ __launch_bounds__(256) void scatter_kernel(
    const float* __restrict__ x, const int* __restrict__ edge_index,
    const float* __restrict__ weights, float* __restrict__ readout)
{
    const int gid = blockIdx.x * 256 + threadIdx.x;
    const int e = gid >> 5;
    const int c = gid & 31;
    if (e >= N_EDGES) return;
    const int row = edge_index[e];
    const int col = edge_index[N_EDGES + e];
    const float w = weights[col];
    const float4 xv = ((const float4*)(x + (size_t)col * IN_DIM))[c];
    float* dst = readout + (size_t)row * IN_DIM + c * 4;
    atomicAdd(dst + 0, xv.x * w);
    atomicAdd(dst + 1, xv.y * w);
    atomicAdd(dst + 2, xv.z * w);
    atomicAdd(dst + 3, xv.w * w);
}

// ---------------------------------------------------------------------------
// Prompt v9 (R10): LDS-staged coalesced row IO.
// v8's per-thread-row global access made every float4 instruction touch 64
// cache lines (512B lane stride) on the out-read, x-read AND out-write ->
// ~16x L2 request amplification; prompt sat at ~110 us vs ~45 us floor.
// v9: block stages its 64 rows through LDS (stride 132 floats: hot per-row
// float4 reads start at bank (lane+4k)%32 -> 2 lanes/bank = free; cold
// stage/store phases are 4-way, acceptable). h exchange reuses the same
// buffer (barrier-separated). Global IO is 100% coalesced float4.
// In-place safe: block touches only its own 64 rows of out.
// LDS = 64*132*4 = 33.8 KB -> 4 blocks/CU.
// ---------------------------------------------------------------------------
#define RB_STRIDE 132
__global__ __launch_bounds__(256) void prompt_kernel(
    const float* __restrict__ x, float* __restrict__ out /* = readout */,
    const float* __restrict__ W1, const float* __restrict__ b1,
    const float* __restrict__ W2, const float* __restrict__ b2)
{
    __shared__ float rb[64 * RB_STRIDE];
    const int t    = threadIdx.x;
    const int lane = t & 63;
    const int w    = __builtin_amdgcn_readfirstlane(t >> 6);
    const int jb   = 16 * w;   // layer1 h-col base  (HIDDEN/4 = 16)
    const int ob   = 32 * w;   // layer2 out-col base (IN_DIM/4 = 32)
    const int fbase = blockIdx.x * 2048;          // block's float4 window
    const int FTOT  = N_NODES * (IN_DIM / 4);     // 3,200,000

    // ---- stage readout rows (coalesced) ----
    const float4* out4c = (const float4*)out;
#pragma unroll
    for (int i = 0; i < 8; ++i) {
        const int f = t + i * 256;                // 0..2047
        if (fbase + f < FTOT) {
            const int row = f >> 5, c4 = f & 31;
            *(float4*)&rb[row * RB_STRIDE + c4 * 4] = out4c[fbase + f];
        }
    }
    __syncthreads();

    // ---- layer1: thread = (node=lane, h-cols jb..jb+16) ----
    float acc[16];
#pragma unroll
    for (int j = 0; j < 16; ++j) acc[j] = b1[jb + j];

    for (int k4 = 0; k4 < IN_DIM / 4; ++k4) {
        const float4 a = *(const float4*)&rb[lane * RB_STRIDE + 4 * k4];
#pragma unroll
        for (int j = 0; j < 16; ++j) {
            acc[j] += a.x * W1[(4 * k4 + 0) * HIDDEN + jb + j];
            acc[j] += a.y * W1[(4 * k4 + 1) * HIDDEN + jb + j];
            acc[j] += a.z * W1[(4 * k4 + 2) * HIDDEN + jb + j];
            acc[j] += a.w * W1[(4 * k4 + 3) * HIDDEN + jb + j];
        }
    }
    __syncthreads();   // all row reads done before h overwrites rb

    // ---- write relu(h) into rb[lane][jb..jb+16) ----
#pragma unroll
    for (int q = 0; q < 4; ++q) {
        float4 hv;
        hv.x = fmaxf(acc[4 * q + 0], 0.f);
        hv.y = fmaxf(acc[4 * q + 1], 0.f);
        hv.z = fmaxf(acc[4 * q + 2], 0.f);
        hv.w = fmaxf(acc[4 * q + 3], 0.f);
        *(float4*)&rb[lane * RB_STRIDE + jb + 4 * q] = hv;
    }
    __syncthreads();

    // ---- layer2: thread = (node=lane, out-cols ob..ob+32) ----
    float acc2[32];
#pragma unroll
    for (int jj = 0; jj < 32; ++jj) acc2[jj] = b2[ob + jj];
#pragma unroll
    for (int q = 0; q < 16; ++q) {
        const float4 h4 = *(const float4*)&rb[lane * RB_STRIDE + 4 * q];
#pragma unroll
        for (int jj = 0; jj < 32; ++jj)
            acc2[jj] += h4.x * W2[(4 * q + 0) * IN_DIM + ob + jj];
#pragma unroll
        for (int jj = 0; jj < 32; ++jj)
            acc2[jj] += h4.y * W2[(4 * q + 1) * IN_DIM + ob + jj];
#pragma unroll
        for (int jj = 0; jj < 32; ++jj)
            acc2[jj] += h4.z * W2[(4 * q + 2) * IN_DIM + ob + jj];
#pragma unroll
        for (int jj = 0; jj < 32; ++jj)
            acc2[jj] += h4.w * W2[(4 * q + 3) * IN_DIM + ob + jj];
    }
    __syncthreads();   // all h reads done before prompt overwrites rb

    // ---- write prompts into rb[lane][ob..ob+32) ----
#pragma unroll
    for (int q = 0; q < 8; ++q) {
        float4 pv;
        pv.x = acc2[4 * q + 0];
        pv.y = acc2[4 * q + 1];
        pv.z = acc2[4 * q + 2];
        pv.w = acc2[4 * q + 3];
        *(float4*)&rb[lane * RB_STRIDE + ob + 4 * q] = pv;
    }
    __syncthreads();

    // ---- coalesced store: out = x + prompts ----
    const float4* x4 = (const float4*)x;
    float4* o4 = (float4*)out;
#pragma unroll
    for (int i = 0; i < 8; ++i) {
        const int f = t + i * 256;
        if (fbase + f < FTOT) {
            const int row = f >> 5, c4 = f & 31;
            const float4 pv = *(const float4*)&rb[row * RB_STRIDE + c4 * 4];
            const float4 xv = x4[fbase + f];
            float4 ov;
            ov.x = xv.x + pv.x;
            ov.y = xv.y + pv.y;
            ov.z = xv.z + pv.z;
            ov.w = xv.w + pv.w;
            o4[fbase + f] = ov;
        }
    }
}

// ---------------------------------------------------------------------------
extern "C" void kernel_launch(void* const* d_in, const int* in_sizes, int n_in,
                              void* d_out, int out_size, void* d_ws, size_t ws_size,
                              hipStream_t stream)
{
    const float* x          = (const float*)d_in[0];
    const int*   edge_index = (const int*)d_in[1];   // int32 (JAX x64 disabled)
    const float* W_sim      = (const float*)d_in[2];
    const float* b_sim      = (const float*)d_in[3];
    const float* w_vec      = (const float*)d_in[4];
    const float* b_vec      = (const float*)d_in[5];
    const float* W1         = (const float*)d_in[6];
    const float* b1         = (const float*)d_in[7];
    const float* W2         = (const float*)d_in[8];
    const float* b2         = (const float*)d_in[9];

    float* out = (float*)d_out;
    float* wsf = (float*)d_ws;
    int*   wsi = (int*)d_ws;

    float* weights = wsf + WS_WEIGHTS;

    if (ws_size >= (size_t)WS_TOTAL2 * 4) {
        // ------- Path A (R10): bf16 mirror + rank trick + x4 binning -------
        int* counts  = wsi + WS_COUNTS;
        int* counter = wsi + WS_COUNTER;
        int* base    = wsi + WS_BASE;
        int* bucket  = wsi + WS_BUCKET;
        unsigned int*   xb16u = (unsigned int*)(wsi + WS_XBF16);
        unsigned short* xb16  = (unsigned short*)xb16u;
        int* rank    = (int*)out;   // out is dead until gather rewrites it

        hipMemsetAsync(wsi + WS_COUNTS, 0, (size_t)(WS_BASE - WS_COUNTS) * 4, stream);

        gate_hist_conv_kernel<<<NB_HIST4 + NB_CONV + NB_GATE, 256, 0, stream>>>(
            x, W_sim, b_sim, w_vec, b_vec, weights, edge_index, counts, rank, xb16u);
        alloc_kernel<<<(N_NODES + 255) / 256, 256, 0, stream>>>(counts, base, counter);
        fill_kernel<<<NB_HIST4, 256, 0, stream>>>(edge_index, base, rank, bucket);
        gather_bf16_kernel<<<N_NODES / 4, 256, 0, stream>>>(xb16, weights, counts, base, bucket, out);
    } else if (ws_size >= (size_t)WS_TOTAL * 4) {
        // ------- Path B (R7 structure, f32 gather) -------
        int* counts  = wsi + WS_COUNTS;
        int* counter = wsi + WS_COUNTER;
        int* base    = wsi + WS_BASE;
        int* bucket  = wsi + WS_BUCKET;
        int* rank    = (int*)out;

        hipMemsetAsync(wsi + WS_COUNTS, 0, (size_t)(WS_BASE - WS_COUNTS) * 4, stream);

        gate_hist_kernel<<<NB_HIST + NB_GATE, 256, 0, stream>>>(
            x, W_sim, b_sim, w_vec, b_vec, weights, edge_index, counts, rank);
        alloc_kernel<<<(N_NODES + 255) / 256, 256, 0, stream>>>(counts, base, counter);
        fill_kernel<<<NB_HIST4, 256, 0, stream>>>(edge_index, base, rank, bucket);
        gather_kernel<<<N_NODES / 4, 256, 0, stream>>>(x, weights, counts, base, bucket, out);
    } else {
        // ------- Path C: fallback scatter -------
        gate_kernel<<<NB_GATE, 256, 0, stream>>>(x, W_sim, b_sim, w_vec, b_vec, weights);
        const int n4 = N_NODES * IN_DIM / 4;
        zero_f4_kernel<<<(n4 + 255) / 256, 256, 0, stream>>>((float4*)out, n4);
        scatter_kernel<<<(N_EDGES * 32) / 256, 256, 0, stream>>>(x, edge_index, weights, out);
    }

    prompt_kernel<<<NB_GATE, 256, 0, stream>>>(x, out, W1, b1, W2, b2);
}

// Round 12
// 412.340 us; speedup vs baseline: 1.0845x; 1.0845x over previous
//
#include <hip/hip_runtime.h>
#include <math.h>

#define N_NODES 100000
#define IN_DIM  128
#define HIDDEN  64
#define N_EDGES 1600000

// ---------------------------------------------------------------------------
// R12 path A'' workspace (4-byte units), LINE-PADDED counts:
//   [0,       100000)   weights  (float)   per-node gate
//   [100000, 1700000)   counts   (int x16) ONE COUNTER PER 64B LINE: row*16
//   [1700000,1800000)   base     (int)     per-node segment base in bucket
//   [1800000,3400000)   bucket   (int)     edge source (col) grouped by row
//   [3400000,9800000)   x_bf16   (ushort)  RNE bf16 mirror of x
// Total 9,800,000 words = 39.2 MB — proven available (R9 mega path ran).
// rank[e] scratch lives in the OUT buffer (dead until gather rewrites it).
//
// Atomic-phase evidence ledger:
//   R5  fill w/ cursor atomics:   117 us, VALU 0.4%   (atomic-paced)
//   R7  fill atomic-free:         ~52 us              (-65: atomics were it)
//   R8  hist 1/thread:            117 us total ghc    (atomic-paced)
//   R9  hist + dependent store:   197 us              (chain length doubles t)
//   R10 hist x4/thread:           129-143 us          (batching hurts)
// => not ILP-fixable. R12 tests LINE-CONFLICT hypothesis: 16 counters/64B
//    line x 256 atomics/line serialize at the L2; padding to 1 counter/line
//    parallelizes the per-line RMW queues.
// ---------------------------------------------------------------------------
#define CSTRIDE     16                 // ints per counter slot (64B line)
#define WS3_WEIGHTS 0
#define WS3_COUNTS  100000
#define WS3_BASE    1700000
#define WS3_BUCKET  1800000
#define WS3_XBF16   3400000
#define WS3_TOTAL   9800000            // 39.2 MB

// Legacy R8 layout (path A fallback, 33.6 MB — verified):
#define WS_WEIGHTS 0
#define WS_COUNTS  100000
#define WS_CURSOR  200000
#define WS_COUNTER 300000
#define WS_BASE    300016
#define WS_BUCKET  400016
#define WS_XBF16   2000016
#define WS_TOTAL   2000016             // path B requirement
#define WS_TOTAL2  (WS_XBF16 + 6400000)

#define NB_GATE  ((N_NODES + 63) / 64)               // 1563
#define NB_HIST  ((N_EDGES + 255) / 256)             // 6250 (1 edge/thread)
#define NB_FILL4 ((N_EDGES / 4 + 255) / 256)         // 1563 (4 edges/thread)
#define NB_CONV  ((N_NODES * IN_DIM / 8 + 255) / 256)// 6250 (exact)

__global__ __launch_bounds__(256) void zero_f4_kernel(float4* __restrict__ p, int n4)
{
    const int i = blockIdx.x * 256 + threadIdx.x;
    if (i < n4) p[i] = make_float4(0.f, 0.f, 0.f, 0.f);
}

__device__ __forceinline__ unsigned int bf16_rne(float f)
{
    const unsigned int u = __float_as_uint(f);
    return (u + 0x7FFFu + ((u >> 16) & 1u)) >> 16;
}

// ---------------------------------------------------------------------------
// Gate body (v6, verified): 4 threads per node, 64 nodes per block;
// wave-uniform W_sim addresses; 4-wave LDS reduction.
// ---------------------------------------------------------------------------
__device__ __forceinline__ void gate_body(
    int gblock,
    const float* __restrict__ x, const float* __restrict__ W_sim,
    const float* __restrict__ b_sim, const float* __restrict__ w_vec,
    const float* __restrict__ b_vec, float* __restrict__ weights)
{
    __shared__ float part[4][64];
    const int lane  = threadIdx.x & 63;
    const int w     = __builtin_amdgcn_readfirstlane(threadIdx.x >> 6);
    const int jb    = 16 * w;
    const int node  = gblock * 64 + lane;
    const bool valid = node < N_NODES;
    const float4* xr = (const float4*)(x + (size_t)(valid ? node : 0) * IN_DIM);

    float acc[16];
#pragma unroll
    for (int j = 0; j < 16; ++j) acc[j] = b_sim[jb + j];

    for (int k4 = 0; k4 < IN_DIM / 4; ++k4) {
        const float4 a = xr[k4];
#pragma unroll
        for (int j = 0; j < 16; ++j) {
            acc[j] += a.x * W_sim[(4 * k4 + 0) * HIDDEN + jb + j];
            acc[j] += a.y * W_sim[(4 * k4 + 1) * HIDDEN + jb + j];
            acc[j] += a.z * W_sim[(4 * k4 + 2) * HIDDEN + jb + j];
            acc[j] += a.w * W_sim[(4 * k4 + 3) * HIDDEN + jb + j];
        }
    }

    float p = 0.f;
#pragma unroll
    for (int j = 0; j < 16; ++j)
        p += tanhf(acc[j]) * w_vec[jb + j];

    part[w][lane] = p;
    __syncthreads();

    if (threadIdx.x < 64) {
        const float g = part[0][lane] + part[1][lane] + part[2][lane] + part[3][lane];
        if (valid)
            weights[node] = 1.f / (1.f + expf(-(g + b_vec[0])));
    }
}

// Standalone gate (fallback path C only).
__global__ __launch_bounds__(256) void gate_kernel(
    const float* __restrict__ x, const float* __restrict__ W_sim,
    const float* __restrict__ b_sim, const float* __restrict__ w_vec,
    const float* __restrict__ b_vec, float* __restrict__ weights)
{
    gate_body(blockIdx.x, x, W_sim, b_sim, w_vec, b_vec, weights);
}

// ---------------------------------------------------------------------------
// R12 path A'': fused gate + hist(1/thread, LINE-PADDED counts) + conv.
// Hist blocks FIRST (atomic pacer starts at t=0); conv+gate backfill.
// ---------------------------------------------------------------------------
__global__ __launch_bounds__(256) void gate_hist_conv_p_kernel(
    const float* __restrict__ x, const float* __restrict__ W_sim,
    const float* __restrict__ b_sim, const float* __restrict__ w_vec,
    const float* __restrict__ b_vec, float* __restrict__ weights,
    const int* __restrict__ edge_index, int* __restrict__ counts /* padded */,
    int* __restrict__ rank /* = out buffer scratch */,
    unsigned int* __restrict__ xb16)
{
    if (blockIdx.x < NB_HIST) {
        const int e = blockIdx.x * 256 + threadIdx.x;
        if (e < N_EDGES) {
            const int row = edge_index[e];
            rank[e] = atomicAdd(&counts[row << 4], 1);   // one counter / 64B line
        }
        return;
    }
    if (blockIdx.x < NB_HIST + NB_CONV) {
        const int t = (blockIdx.x - NB_HIST) * 256 + threadIdx.x; // [0,1.6M)
        const float4* src = (const float4*)x;
        const float4 a = src[2 * t + 0];
        const float4 b = src[2 * t + 1];
        uint4 o;
        o.x = bf16_rne(a.x) | (bf16_rne(a.y) << 16);
        o.y = bf16_rne(a.z) | (bf16_rne(a.w) << 16);
        o.z = bf16_rne(b.x) | (bf16_rne(b.y) << 16);
        o.w = bf16_rne(b.z) | (bf16_rne(b.w) << 16);
        ((uint4*)xb16)[t] = o;
        return;
    }
    gate_body(blockIdx.x - NB_HIST - NB_CONV, x, W_sim, b_sim, w_vec, b_vec, weights);
}

// alloc over padded counts -> compact base.
__global__ __launch_bounds__(256) void alloc_p_kernel(
    const int* __restrict__ counts /* padded */, int* __restrict__ base,
    int* __restrict__ counter /* 1 int, in base[N_NODES] slot? no — passed */)
{
    const int node = blockIdx.x * 256 + threadIdx.x;
    const int lane = threadIdx.x & 63;
    const int c = (node < N_NODES) ? counts[node << 4] : 0;

    int incl = c;
#pragma unroll
    for (int off = 1; off < 64; off <<= 1) {
        int v = __shfl_up(incl, off, 64);
        if (lane >= off) incl += v;
    }
    const int excl = incl - c;
    int wbase = 0;
    if (lane == 63) wbase = atomicAdd(counter, incl);
    wbase = __shfl(wbase, 63, 64);

    if (node < N_NODES) base[node] = wbase + excl;
}

// ---------------------------------------------------------------------------
// Fill (R10 x4 form, atomic-free): 4 independent load(base)+store(bucket)
// chains per thread; edge/rank IO int4-coalesced.
// ---------------------------------------------------------------------------
__global__ __launch_bounds__(256) void fill_kernel(
    const int* __restrict__ edge_index, const int* __restrict__ base,
    const int* __restrict__ rank, int* __restrict__ bucket)
{
    const int t4 = blockIdx.x * 256 + threadIdx.x;
    if (t4 * 4 >= N_EDGES) return;
    const int4 rows = ((const int4*)edge_index)[t4];
    const int4 cols = ((const int4*)(edge_index + N_EDGES))[t4];
    const int4 rk   = ((const int4*)rank)[t4];
    const int b0 = base[rows.x];
    const int b1 = base[rows.y];
    const int b2 = base[rows.z];
    const int b3 = base[rows.w];
    bucket[b0 + rk.x] = cols.x;
    bucket[b1 + rk.y] = cols.y;
    bucket[b2 + rk.z] = cols.z;
    bucket[b3 + rk.w] = cols.w;
}

// ---------------------------------------------------------------------------
// Gather (bf16 mirror, padded counts): bytes-bound form (R7/R8 verified
// ILP-insensitive). m read from counts[node*16].
// ---------------------------------------------------------------------------
__global__ __launch_bounds__(256) void gather_bf16_p_kernel(
    const unsigned short* __restrict__ xb, const float* __restrict__ weights,
    const int* __restrict__ counts /* padded */, const int* __restrict__ base,
    const int* __restrict__ bucket, float* __restrict__ readout)
{
    const int wave = threadIdx.x >> 6;
    const int lane = threadIdx.x & 63;
    const int half = lane >> 5;
    const int l32  = lane & 31;
    const int node = blockIdx.x * 4 + wave;
    if (node >= N_NODES) return;

    const int m = counts[node << 4];
    const int b = base[node];
    const int m0  = (m + 1) >> 1;
    const int beg = half ? m0 : 0;
    const int end = half ? m  : m0;

    float4 acc0 = make_float4(0.f, 0.f, 0.f, 0.f);
    float4 acc1 = make_float4(0.f, 0.f, 0.f, 0.f);

#define BF2F(us) __uint_as_float(((unsigned int)(us)) << 16)
    int i = beg;
    for (; i + 2 <= end; i += 2) {
        const int c0 = bucket[b + i + 0];
        const int c1 = bucket[b + i + 1];
        const float w0 = weights[c0];
        const float w1 = weights[c1];
        const ushort4 v0 = ((const ushort4*)(xb + (size_t)c0 * IN_DIM))[l32];
        const ushort4 v1 = ((const ushort4*)(xb + (size_t)c1 * IN_DIM))[l32];
        acc0.x += BF2F(v0.x) * w0; acc0.y += BF2F(v0.y) * w0;
        acc0.z += BF2F(v0.z) * w0; acc0.w += BF2F(v0.w) * w0;
        acc1.x += BF2F(v1.x) * w1; acc1.y += BF2F(v1.y) * w1;
        acc1.z += BF2F(v1.z) * w1; acc1.w += BF2F(v1.w) * w1;
    }
    if (i < end) {
        const int c = bucket[b + i];
        const float wv = weights[c];
        const ushort4 v = ((const ushort4*)(xb + (size_t)c * IN_DIM))[l32];
        acc0.x += BF2F(v.x) * wv; acc0.y += BF2F(v.y) * wv;
        acc0.z += BF2F(v.z) * wv; acc0.w += BF2F(v.w) * wv;
    }
#undef BF2F
    acc0.x += acc1.x; acc0.y += acc1.y; acc0.z += acc1.z; acc0.w += acc1.w;

    acc0.x += __shfl(acc0.x, lane ^ 32, 64);
    acc0.y += __shfl(acc0.y, lane ^ 32, 64);
    acc0.z += __shfl(acc0.z, lane ^ 32, 64);
    acc0.w += __shfl(acc0.w, lane ^ 32, 64);

    if (half == 0)
        ((float4*)(readout + (size_t)node * IN_DIM))[l32] = acc0;
}

// ===========================================================================
// Legacy R8 path A kernels (33.6 MB fallback — verified R8).
// ===========================================================================
__global__ __launch_bounds__(256) void gate_hist_conv_kernel(
    const float* __restrict__ x, const float* __restrict__ W_sim,
    const float* __restrict__ b_sim, const float* __restrict__ w_vec,
    const float* __restrict__ b_vec, float* __restrict__ weights,
    const int* __restrict__ edge_index, int* __restrict__ counts,
    int* __restrict__ rank, unsigned int* __restrict__ xb16)
{
    if (blockIdx.x < NB_CONV) {
        const int t = blockIdx.x * 256 + threadIdx.x;
        const float4* src = (const float4*)x;
        const float4 a = src[2 * t + 0];
        const float4 b = src[2 * t + 1];
        uint4 o;
        o.x = bf16_rne(a.x) | (bf16_rne(a.y) << 16);
        o.y = bf16_rne(a.z) | (bf16_rne(a.w) << 16);
        o.z = bf16_rne(b.x) | (bf16_rne(b.y) << 16);
        o.w = bf16_rne(b.z) | (bf16_rne(b.w) << 16);
        ((uint4*)xb16)[t] = o;
        return;
    }
    if (blockIdx.x < NB_CONV + NB_HIST) {
        const int e = (blockIdx.x - NB_CONV) * 256 + threadIdx.x;
        if (e < N_EDGES) {
            const int row = edge_index[e];
            rank[e] = atomicAdd(&counts[row], 1);
        }
        return;
    }
    gate_body(blockIdx.x - NB_CONV - NB_HIST, x, W_sim, b_sim, w_vec, b_vec, weights);
}

__global__ __launch_bounds__(256) void gate_hist_kernel(
    const float* __restrict__ x, const float* __restrict__ W_sim,
    const float* __restrict__ b_sim, const float* __restrict__ w_vec,
    const float* __restrict__ b_vec, float* __restrict__ weights,
    const int* __restrict__ edge_index, int* __restrict__ counts,
    int* __restrict__ rank)
{
    if (blockIdx.x < NB_HIST) {
        const int e = blockIdx.x * 256 + threadIdx.x;
        if (e < N_EDGES) {
            const int row = edge_index[e];
            rank[e] = atomicAdd(&counts[row], 1);
        }
        return;
    }
    gate_body(blockIdx.x - NB_HIST, x, W_sim, b_sim, w_vec, b_vec, weights);
}

__global__ __launch_bounds__(256) void alloc_kernel(
    const int* __restrict__ counts, int* __restrict__ base, int* __restrict__ counter)
{
    const int node = blockIdx.x * 256 + threadIdx.x;
    const int lane = threadIdx.x & 63;
    const int c = (node < N_NODES) ? counts[node] : 0;

    int incl = c;
#pragma unroll
    for (int off = 1; off < 64; off <<= 1) {
        int v = __shfl_up(incl, off, 64);
        if (lane >= off) incl += v;
    }
    const int excl = incl - c;
    int wbase = 0;
    if (lane == 63) wbase = atomicAdd(counter, incl);
    wbase = __shfl(wbase, 63, 64);

    if (node < N_NODES) base[node] = wbase + excl;
}

__global__ __launch_bounds__(256) void gather_bf16_kernel(
    const unsigned short* __restrict__ xb, const float* __restrict__ weights,
    const int* __restrict__ counts, const int* __restrict__ base,
    const int* __restrict__ bucket, float* __restrict__ readout)
{
    const int wave = threadIdx.x >> 6;
    const int lane = threadIdx.x & 63;
    const int half = lane >> 5;
    const int l32  = lane & 31;
    const int node = blockIdx.x * 4 + wave;
    if (node >= N_NODES) return;

    const int m = counts[node];
    const int b = base[node];
    const int m0  = (m + 1) >> 1;
    const int beg = half ? m0 : 0;
    const int end = half ? m  : m0;

    float4 acc0 = make_float4(0.f, 0.f, 0.f, 0.f);
    float4 acc1 = make_float4(0.f, 0.f, 0.f, 0.f);

#define BF2F(us) __uint_as_float(((unsigned int)(us)) << 16)
    int i = beg;
    for (; i + 2 <= end; i += 2) {
        const int c0 = bucket[b + i + 0];
        const int c1 = bucket[b + i + 1];
        const float w0 = weights[c0];
        const float w1 = weights[c1];
        const ushort4 v0 = ((const ushort4*)(xb + (size_t)c0 * IN_DIM))[l32];
        const ushort4 v1 = ((const ushort4*)(xb + (size_t)c1 * IN_DIM))[l32];
        acc0.x += BF2F(v0.x) * w0; acc0.y += BF2F(v0.y) * w0;
        acc0.z += BF2F(v0.z) * w0; acc0.w += BF2F(v0.w) * w0;
        acc1.x += BF2F(v1.x) * w1; acc1.y += BF2F(v1.y) * w1;
        acc1.z += BF2F(v1.z) * w1; acc1.w += BF2F(v1.w) * w1;
    }
    if (i < end) {
        const int c = bucket[b + i];
        const float wv = weights[c];
        const ushort4 v = ((const ushort4*)(xb + (size_t)c * IN_DIM))[l32];
        acc0.x += BF2F(v.x) * wv; acc0.y += BF2F(v.y) * wv;
        acc0.z += BF2F(v.z) * wv; acc0.w += BF2F(v.w) * wv;
    }
#undef BF2F
    acc0.x += acc1.x; acc0.y += acc1.y; acc0.z += acc1.z; acc0.w += acc1.w;

    acc0.x += __shfl(acc0.x, lane ^ 32, 64);
    acc0.y += __shfl(acc0.y, lane ^ 32, 64);
    acc0.z += __shfl(acc0.z, lane ^ 32, 64);
    acc0.w += __shfl(acc0.w, lane ^ 32, 64);

    if (half == 0)
        ((float4*)(readout + (size_t)node * IN_DIM))[l32] = acc0;
}

__global__ __launch_bounds__(256) void gather_kernel(
    const float* __restrict__ x, const float* __restrict__ weights,
    const int* __restrict__ counts, const int* __restrict__ base,
    const int* __restrict__ bucket, float* __restrict__ readout)
{
    const int wave = threadIdx.x >> 6;
    const int lane = threadIdx.x & 63;
    const int half = lane >> 5;
    const int l32  = lane & 31;
    const int node = blockIdx.x * 4 + wave;
    if (node >= N_NODES) return;

    const int m = counts[node];
    const int b = base[node];
    const int m0  = (m + 1) >> 1;
    const int beg = half ? m0 : 0;
    const int end = half ? m  : m0;

    float4 acc0 = make_float4(0.f, 0.f, 0.f, 0.f);
    float4 acc1 = make_float4(0.f, 0.f, 0.f, 0.f);

    int i = beg;
    for (; i + 2 <= end; i += 2) {
        const int c0 = bucket[b + i + 0];
        const int c1 = bucket[b + i + 1];
        const float w0 = weights[c0];
        const float w1 = weights[c1];
        const float4 r0 = ((const float4*)(x + (size_t)c0 * IN_DIM))[l32];
        const float4 r1 = ((const float4*)(x + (size_t)c1 * IN_DIM))[l32];
        acc0.x += r0.x * w0; acc0.y += r0.y * w0; acc0.z += r0.z * w0; acc0.w += r0.w * w0;
        acc1.x += r1.x * w1; acc1.y += r1.y * w1; acc1.z += r1.z * w1; acc1.w += r1.w * w1;
    }
    if (i < end) {
        const int c = bucket[b + i];
        const float wv = weights[c];
        const float4 r = ((const float4*)(x + (size_t)c * IN_DIM))[l32];
        acc0.x += r.x * wv; acc0.y += r.y * wv; acc0.z += r.z * wv; acc0.w += r.w * wv;
    }
    acc0.x += acc1.x; acc0.y += acc1.y; acc0.z += acc1.z; acc0.w += acc1.w;

    acc0.x += __shfl(acc0.x, lane ^ 32, 64);
    acc0.y += __shfl(acc0.y, lane ^ 32, 64);
    acc0.z += __shfl(acc0.z, lane ^ 32, 64);
    acc0.w += __shfl(acc0.w, lane ^ 32, 64);

    if (half == 0)
        ((float4*)(readout + (size_t)node * IN_DIM))[l32] = acc0;
}

__global__ __launch_bounds__(256) void scatter_kernel(
    const float* __restrict__ x, const int* __restrict__ edge_index,
    const float* __restrict__ weights, float* __restrict__ readout)
{
    const int gid = blockIdx.x * 256 + threadIdx.x;
    const int e = gid >> 5;
    const int c = gid & 31;
    if (e >= N_EDGES) return;
    const int row = edge_index[e];
    const int col = edge_index[N_EDGES + e];
    const float w = weights[col];
    const float4 xv = ((const float4*)(x + (size_t)col * IN_DIM))[c];
    float* dst = readout + (size_t)row * IN_DIM + c * 4;
    atomicAdd(dst + 0, xv.x * w);
    atomicAdd(dst + 1, xv.y * w);
    atomicAdd(dst + 2, xv.z * w);
    atomicAdd(dst + 3, xv.w * w);
}

// ---------------------------------------------------------------------------
// Prompt v9 (R10/R11): LDS-staged coalesced row IO. Global IO 100% coalesced
// float4; per-row LDS reads 2-way bank aliased (free). In-place safe.
// LDS = 64*132*4 = 33.8 KB -> 4 blocks/CU.
// ---------------------------------------------------------------------------
#define RB_STRIDE 132
__global__ __launch_bounds__(256) void prompt_kernel(
    const float* __restrict__ x, float* __restrict__ out /* = readout */,
    const float* __restrict__ W1, const float* __restrict__ b1,
    const float* __restrict__ W2, const float* __restrict__ b2)
{
    __shared__ float rb[64 * RB_STRIDE];
    const int t    = threadIdx.x;
    const int lane = t & 63;
    const int w    = __builtin_amdgcn_readfirstlane(t >> 6);
    const int jb   = 16 * w;
    const int ob   = 32 * w;
    const int fbase = blockIdx.x * 2048;
    const int FTOT  = N_NODES * (IN_DIM / 4);

    const float4* out4c = (const float4*)out;
#pragma unroll
    for (int i = 0; i < 8; ++i) {
        const int f = t + i * 256;
        if (fbase + f < FTOT) {
            const int row = f >> 5, c4 = f & 31;
            *(float4*)&rb[row * RB_STRIDE + c4 * 4] = out4c[fbase + f];
        }
    }
    __syncthreads();

    float acc[16];
#pragma unroll
    for (int j = 0; j < 16; ++j) acc[j] = b1[jb + j];

    for (int k4 = 0; k4 < IN_DIM / 4; ++k4) {
        const float4 a = *(const float4*)&rb[lane * RB_STRIDE + 4 * k4];
#pragma unroll
        for (int j = 0; j < 16; ++j) {
            acc[j] += a.x * W1[(4 * k4 + 0) * HIDDEN + jb + j];
            acc[j] += a.y * W1[(4 * k4 + 1) * HIDDEN + jb + j];
            acc[j] += a.z * W1[(4 * k4 + 2) * HIDDEN + jb + j];
            acc[j] += a.w * W1[(4 * k4 + 3) * HIDDEN + jb + j];
        }
    }
    __syncthreads();

#pragma unroll
    for (int q = 0; q < 4; ++q) {
        float4 hv;
        hv.x = fmaxf(acc[4 * q + 0], 0.f);
        hv.y = fmaxf(acc[4 * q + 1], 0.f);
        hv.z = fmaxf(acc[4 * q + 2], 0.f);
        hv.w = fmaxf(acc[4 * q + 3], 0.f);
        *(float4*)&rb[lane * RB_STRIDE + jb + 4 * q] = hv;
    }
    __syncthreads();

    float acc2[32];
#pragma unroll
    for (int jj = 0; jj < 32; ++jj) acc2[jj] = b2[ob + jj];
#pragma unroll
    for (int q = 0; q < 16; ++q) {
        const float4 h4 = *(const float4*)&rb[lane * RB_STRIDE + 4 * q];
#pragma unroll
        for (int jj = 0; jj < 32; ++jj)
            acc2[jj] += h4.x * W2[(4 * q + 0) * IN_DIM + ob + jj];
#pragma unroll
        for (int jj = 0; jj < 32; ++jj)
            acc2[jj] += h4.y * W2[(4 * q + 1) * IN_DIM + ob + jj];
#pragma unroll
        for (int jj = 0; jj < 32; ++jj)
            acc2[jj] += h4.z * W2[(4 * q + 2) * IN_DIM + ob + jj];
#pragma unroll
        for (int jj = 0; jj < 32; ++jj)
            acc2[jj] += h4.w * W2[(4 * q + 3) * IN_DIM + ob + jj];
    }
    __syncthreads();

#pragma unroll
    for (int q = 0; q < 8; ++q) {
        float4 pv;
        pv.x = acc2[4 * q + 0];
        pv.y = acc2[4 * q + 1];
        pv.z = acc2[4 * q + 2];
        pv.w = acc2[4 * q + 3];
        *(float4*)&rb[lane * RB_STRIDE + ob + 4 * q] = pv;
    }
    __syncthreads();

    const float4* x4 = (const float4*)x;
    float4* o4 = (float4*)out;
#pragma unroll
    for (int i = 0; i < 8; ++i) {
        const int f = t + i * 256;
        if (fbase + f < FTOT) {
            const int row = f >> 5, c4 = f & 31;
            const float4 pv = *(const float4*)&rb[row * RB_STRIDE + c4 * 4];
            const float4 xv = x4[fbase + f];
            float4 ov;
            ov.x = xv.x + pv.x;
            ov.y = xv.y + pv.y;
            ov.z = xv.z + pv.z;
            ov.w = xv.w + pv.w;
            o4[fbase + f] = ov;
        }
    }
}

// ---------------------------------------------------------------------------
extern "C" void kernel_launch(void* const* d_in, const int* in_sizes, int n_in,
                              void* d_out, int out_size, void* d_ws, size_t ws_size,
                              hipStream_t stream)
{
    const float* x          = (const float*)d_in[0];
    const int*   edge_index = (const int*)d_in[1];   // int32 (JAX x64 disabled)
    const float* W_sim      = (const float*)d_in[2];
    const float* b_sim      = (const float*)d_in[3];
    const float* w_vec      = (const float*)d_in[4];
    const float* b_vec      = (const float*)d_in[5];
    const float* W1         = (const float*)d_in[6];
    const float* b1         = (const float*)d_in[7];
    const float* W2         = (const float*)d_in[8];
    const float* b2         = (const float*)d_in[9];

    float* out = (float*)d_out;
    float* wsf = (float*)d_ws;
    int*   wsi = (int*)d_ws;

    if (ws_size >= (size_t)WS3_TOTAL * 4) {
        // ------- Path A'' (R12): line-padded counts -------
        float* weights = wsf + WS3_WEIGHTS;
        int* counts  = wsi + WS3_COUNTS;     // padded x16
        int* base    = wsi + WS3_BASE;
        int* bucket  = wsi + WS3_BUCKET;
        unsigned int*   xb16u = (unsigned int*)(wsi + WS3_XBF16);
        unsigned short* xb16  = (unsigned short*)xb16u;
        int* rank    = (int*)out;            // out dead until gather rewrites
        int* counter = wsi + WS3_BASE + N_NODES;  // 1 int, spare slot? no:
        // base region is exactly N_NODES; use last int of counts padding
        // (slot 0 belongs to node 0... use counts[N_NODES*16 - 1]? That line
        // is node 99999's padding; safe: only counts[row*16] are touched.)
        counter = &counts[CSTRIDE * N_NODES - 1];

        // zero padded counts (incl. the counter slot at its tail)
        hipMemsetAsync(counts, 0, (size_t)CSTRIDE * N_NODES * 4, stream);

        gate_hist_conv_p_kernel<<<NB_HIST + NB_CONV + NB_GATE, 256, 0, stream>>>(
            x, W_sim, b_sim, w_vec, b_vec, weights, edge_index, counts, rank, xb16u);
        alloc_p_kernel<<<(N_NODES + 255) / 256, 256, 0, stream>>>(counts, base, counter);
        fill_kernel<<<NB_FILL4, 256, 0, stream>>>(edge_index, base, rank, bucket);
        gather_bf16_p_kernel<<<N_NODES / 4, 256, 0, stream>>>(
            xb16, weights, counts, base, bucket, out);
        prompt_kernel<<<NB_GATE, 256, 0, stream>>>(x, out, W1, b1, W2, b2);
        return;
    }

    float* weights = wsf + WS_WEIGHTS;
    if (ws_size >= (size_t)WS_TOTAL2 * 4) {
        // ------- Path A (R8, verified) -------
        int* counts  = wsi + WS_COUNTS;
        int* counter = wsi + WS_COUNTER;
        int* base    = wsi + WS_BASE;
        int* bucket  = wsi + WS_BUCKET;
        unsigned int*   xb16u = (unsigned int*)(wsi + WS_XBF16);
        unsigned short* xb16  = (unsigned short*)xb16u;
        int* rank    = (int*)out;

        hipMemsetAsync(wsi + WS_COUNTS, 0, (size_t)(WS_BASE - WS_COUNTS) * 4, stream);

        gate_hist_conv_kernel<<<NB_CONV + NB_HIST + NB_GATE, 256, 0, stream>>>(
            x, W_sim, b_sim, w_vec, b_vec, weights, edge_index, counts, rank, xb16u);
        alloc_kernel<<<(N_NODES + 255) / 256, 256, 0, stream>>>(counts, base, counter);
        fill_kernel<<<NB_FILL4, 256, 0, stream>>>(edge_index, base, rank, bucket);
        gather_bf16_kernel<<<N_NODES / 4, 256, 0, stream>>>(xb16, weights, counts, base, bucket, out);
    } else if (ws_size >= (size_t)WS_TOTAL * 4) {
        // ------- Path B (R7 structure, f32 gather) -------
        int* counts  = wsi + WS_COUNTS;
        int* counter = wsi + WS_COUNTER;
        int* base    = wsi + WS_BASE;
        int* bucket  = wsi + WS_BUCKET;
        int* rank    = (int*)out;

        hipMemsetAsync(wsi + WS_COUNTS, 0, (size_t)(WS_BASE - WS_COUNTS) * 4, stream);

        gate_hist_kernel<<<NB_HIST + NB_GATE, 256, 0, stream>>>(
            x, W_sim, b_sim, w_vec, b_vec, weights, edge_index, counts, rank);
        alloc_kernel<<<(N_NODES + 255) / 256, 256, 0, stream>>>(counts, base, counter);
        fill_kernel<<<NB_FILL4, 256, 0, stream>>>(edge_index, base, rank, bucket);
        gather_kernel<<<N_NODES / 4, 256, 0, stream>>>(x, weights, counts, base, bucket, out);
    } else {
        // ------- Path C: fallback scatter -------
        gate_kernel<<<NB_GATE, 256, 0, stream>>>(x, W_sim, b_sim, w_vec, b_vec, weights);
        const int n4 = N_NODES * IN_DIM / 4;
        zero_f4_kernel<<<(n4 + 255) / 256, 256, 0, stream>>>((float4*)out, n4);
        scatter_kernel<<<(N_EDGES * 32) / 256, 256, 0, stream>>>(x, edge_index, weights, out);
    }

    prompt_kernel<<<NB_GATE, 256, 0, stream>>>(x, out, W1, b1, W2, b2);
}